// Round 2
// baseline (149.173 us; speedup 1.0000x reference)
//
#include <hip/hip_runtime.h>
#include <math.h>

static constexpr float PHI_F = 1.61803398874989484820f;

union F4 { float4 v; float f[4]; };

// One 64-lane wave per row (D = 1024 = 64 lanes x 16 elems).
// No LDS, no barriers: reduction is a pure shfl_xor butterfly.
__global__ __launch_bounds__(256, 4) void liquid_echo_kernel(
    const float* __restrict__ x_real,
    const float* __restrict__ x_imag,
    const float* __restrict__ t,
    const float* __restrict__ mem_r,
    const float* __restrict__ mem_i,
    const float* __restrict__ w_query,
    const float* __restrict__ b_query,
    const float* __restrict__ w_osc,
    const float* __restrict__ b_osc,
    float* __restrict__ out_real,
    float* __restrict__ out_imag,
    float* __restrict__ out_alpha)
{
    const int lane = threadIdx.x & 63;
    const int wave = threadIdx.x >> 6;
    const int row  = (blockIdx.x << 2) + wave;      // 4 rows per 256-thread block
    const size_t rbase = (size_t)row << 10;         // row * 1024

    const float trow = t[row];                      // wave-uniform, issued early

    // Burst all row data: 16 loads x 16B = 256B per thread in flight.
    // chunk = j*64 + lane  -> each instruction is 1KB contiguous per wave.
    F4 xr[4], xi[4], mr[4], mi[4];
#pragma unroll
    for (int j = 0; j < 4; ++j) {
        const size_t off = rbase + (size_t)(((j << 6) + lane) << 2);
        xr[j].v = *(const float4*)(x_real + off);
        xi[j].v = *(const float4*)(x_imag + off);
        mr[j].v = *(const float4*)(mem_r + off);
        mi[j].v = *(const float4*)(mem_i + off);
    }
    F4 wq[4], bq[4];
#pragma unroll
    for (int j = 0; j < 4; ++j) {
        const int woff = ((j << 6) + lane) << 2;
        wq[j].v = *(const float4*)(w_query + woff);
        bq[j].v = *(const float4*)(b_query + woff);
    }

    // Phase 1: interference dot products (16 elems/lane)
    float accr = 0.f, acci = 0.f;
#pragma unroll
    for (int j = 0; j < 4; ++j) {
#pragma unroll
        for (int k = 0; k < 4; ++k) {
            float inv = __builtin_amdgcn_rcpf(1.0f + fabsf(wq[j].f[k]));
            float th  = fmaf(xr[j].f[k], inv, bq[j].f[k]);
            float s, c;
            __sincosf(th, &s, &c);
            accr = fmaf(c, mr[j].f[k], fmaf(s, mi[j].f[k], accr));
            acci = fmaf(c, mi[j].f[k], fmaf(-s, mr[j].f[k], acci));
        }
    }

    // Phase-2 weights: wq/bq are dead now, regalloc reuses; L1-resident loads
    // hidden under the 12-op shfl chain below.
    F4 wo[4], bo[4];
#pragma unroll
    for (int j = 0; j < 4; ++j) {
        const int woff = ((j << 6) + lane) << 2;
        wo[j].v = *(const float4*)(w_osc + woff);
        bo[j].v = *(const float4*)(b_osc + woff);
    }

    // In-wave butterfly reduce: every lane ends with the full row sum.
#pragma unroll
    for (int off = 32; off > 0; off >>= 1) {
        accr += __shfl_xor(accr, off, 64);
        acci += __shfl_xor(acci, off, 64);
    }

    // alpha (scale = sqrt(1024) = 32)
    const float mag   = sqrtf(fmaf(accr, accr, acci * acci));
    const float z     = fmaf(mag, 1.0f / 32.0f, -2.0f);
    const float norm  = __builtin_amdgcn_rcpf(1.0f + __expf(-z));   // sigmoid(z)
    const float alpha = __expf(norm - 1.0f);                        // exp(-(1-norm))
    const float beta  = 1.0f - alpha;
    const float tphi2 = 2.0f * PHI_F * trow;

    // Phase 2: blend + oscillate, angle-sum identity:
    //   evolved = (cos, sin)(th_r + th_i)
#pragma unroll
    for (int j = 0; j < 4; ++j) {
        F4 er, ei;
#pragma unroll
        for (int k = 0; k < 4; ++k) {
            float br  = fmaf(alpha, xr[j].f[k], beta * mr[j].f[k]);
            float bi  = fmaf(alpha, xi[j].f[k], beta * mi[j].f[k]);
            float inv = __builtin_amdgcn_rcpf(1.0f + fabsf(wo[j].f[k]));
            float ths = fmaf(br + bi, inv, fmaf(2.0f, bo[j].f[k], tphi2));
            float s, c;
            __sincosf(ths, &s, &c);
            er.f[k] = c;
            ei.f[k] = s;
        }
        const size_t off = rbase + (size_t)(((j << 6) + lane) << 2);
        *(float4*)(out_real + off) = er.v;
        *(float4*)(out_imag + off) = ei.v;
    }

    if (lane == 0) out_alpha[row] = alpha;
}

extern "C" void kernel_launch(void* const* d_in, const int* in_sizes, int n_in,
                              void* d_out, int out_size, void* d_ws, size_t ws_size,
                              hipStream_t stream) {
    const float* x_real = (const float*)d_in[0];
    const float* x_imag = (const float*)d_in[1];
    const float* t      = (const float*)d_in[2];
    const float* mem_r  = (const float*)d_in[3];
    const float* mem_i  = (const float*)d_in[4];
    const float* w_q    = (const float*)d_in[5];
    const float* b_q    = (const float*)d_in[6];
    const float* w_o    = (const float*)d_in[7];
    const float* b_o    = (const float*)d_in[8];

    const int B = in_sizes[2];   // 32768 rows (t has B elements)
    const int D = in_sizes[5];   // 1024 (kernel assumes 1024)

    float* out       = (float*)d_out;
    float* out_real  = out;
    float* out_imag  = out + (size_t)B * (size_t)D;
    float* out_alpha = out + 2ull * (size_t)B * (size_t)D;

    // 4 rows per 256-thread block (one wave per row)
    liquid_echo_kernel<<<B / 4, 256, 0, stream>>>(
        x_real, x_imag, t, mem_r, mem_i, w_q, b_q, w_o, b_o,
        out_real, out_imag, out_alpha);
}

// Round 3
// 146.643 us; speedup vs baseline: 1.0173x; 1.0173x over previous
//
#include <hip/hip_runtime.h>
#include <math.h>

static constexpr float PHI_F = 1.61803398874989484820f;

union F4 { float4 v; float f[4]; };

// One 64-lane wave per row (D = 1024 = 64 lanes x 16 elems), 4 rows/block.
// All 16 row loads are issued as one burst; the vmcnt(0) drain implied by
// __syncthreads() forces them co-resident in registers (no load sinking).
// Weights live in LDS so the streaming data can't thrash them out of L1.
__global__ __launch_bounds__(256) void liquid_echo_kernel(
    const float* __restrict__ x_real,
    const float* __restrict__ x_imag,
    const float* __restrict__ t,
    const float* __restrict__ mem_r,
    const float* __restrict__ mem_i,
    const float* __restrict__ w_query,
    const float* __restrict__ b_query,
    const float* __restrict__ w_osc,
    const float* __restrict__ b_osc,
    float* __restrict__ out_real,
    float* __restrict__ out_imag,
    float* __restrict__ out_alpha)
{
    const int tid  = threadIdx.x;
    const int lane = tid & 63;
    const int wave = tid >> 6;
    const int row  = (blockIdx.x << 2) + wave;
    const size_t rbase = (size_t)row << 10;           // row * 1024

    __shared__ F4 swq[256], sbq[256], swo[256], sbo[256];   // 16 KB

    const float trow = t[row];

    // ---- burst: 16 global loads, 256 B per thread in flight ----
    F4 xr[4], xi[4], mr[4], mi[4];
#pragma unroll
    for (int j = 0; j < 4; ++j) {
        const size_t off = rbase + (size_t)(((j << 6) + lane) << 2);
        xr[j].v = *(const float4*)(x_real + off);
        xi[j].v = *(const float4*)(x_imag + off);
        mr[j].v = *(const float4*)(mem_r + off);
        mi[j].v = *(const float4*)(mem_i + off);
    }

    // ---- stage weights to LDS (once per block) ----
    swq[tid].v = *(const float4*)(w_query + (tid << 2));
    sbq[tid].v = *(const float4*)(b_query + (tid << 2));
    swo[tid].v = *(const float4*)(w_osc   + (tid << 2));
    sbo[tid].v = *(const float4*)(b_osc   + (tid << 2));
    __syncthreads();   // drains vmcnt(0): whole burst lands in registers here

    // ---- phase 1: interference dot products (16 elems/lane) ----
    float accr = 0.f, acci = 0.f;
#pragma unroll
    for (int j = 0; j < 4; ++j) {
        const int c = (j << 6) + lane;
        F4 wq = swq[c], bq = sbq[c];
#pragma unroll
        for (int k = 0; k < 4; ++k) {
            float inv = __builtin_amdgcn_rcpf(1.0f + fabsf(wq.f[k]));
            float th  = fmaf(xr[j].f[k], inv, bq.f[k]);
            float s, c2;
            __sincosf(th, &s, &c2);
            accr = fmaf(c2, mr[j].f[k], fmaf(s, mi[j].f[k], accr));
            acci = fmaf(c2, mi[j].f[k], fmaf(-s, mr[j].f[k], acci));
        }
    }

    // ---- in-wave butterfly reduce: every lane gets the row sum ----
#pragma unroll
    for (int off = 32; off > 0; off >>= 1) {
        accr += __shfl_xor(accr, off, 64);
        acci += __shfl_xor(acci, off, 64);
    }

    // ---- alpha (scale = sqrt(1024) = 32) ----
    const float mag   = sqrtf(fmaf(accr, accr, acci * acci));
    const float z     = fmaf(mag, 1.0f / 32.0f, -2.0f);
    const float norm  = __builtin_amdgcn_rcpf(1.0f + __expf(-z));   // sigmoid(z)
    const float alpha = __expf(norm - 1.0f);                        // exp(-(1-norm))
    const float beta  = 1.0f - alpha;
    const float tphi2 = 2.0f * PHI_F * trow;

    // ---- phase 2: blend + oscillate; angle-sum identity:
    //      evolved = (cos, sin)(th_r + th_i) ----
#pragma unroll
    for (int j = 0; j < 4; ++j) {
        const int c = (j << 6) + lane;
        F4 wo = swo[c], bo = sbo[c];
        F4 er, ei;
#pragma unroll
        for (int k = 0; k < 4; ++k) {
            float br  = fmaf(alpha, xr[j].f[k], beta * mr[j].f[k]);
            float bi  = fmaf(alpha, xi[j].f[k], beta * mi[j].f[k]);
            float inv = __builtin_amdgcn_rcpf(1.0f + fabsf(wo.f[k]));
            float ths = fmaf(br + bi, inv, fmaf(2.0f, bo.f[k], tphi2));
            float s, c2;
            __sincosf(ths, &s, &c2);
            er.f[k] = c2;
            ei.f[k] = s;
        }
        const size_t off = rbase + (size_t)(((j << 6) + lane) << 2);
        *(float4*)(out_real + off) = er.v;
        *(float4*)(out_imag + off) = ei.v;
    }

    if (lane == 0) out_alpha[row] = alpha;
}

extern "C" void kernel_launch(void* const* d_in, const int* in_sizes, int n_in,
                              void* d_out, int out_size, void* d_ws, size_t ws_size,
                              hipStream_t stream) {
    const float* x_real = (const float*)d_in[0];
    const float* x_imag = (const float*)d_in[1];
    const float* t      = (const float*)d_in[2];
    const float* mem_r  = (const float*)d_in[3];
    const float* mem_i  = (const float*)d_in[4];
    const float* w_q    = (const float*)d_in[5];
    const float* b_q    = (const float*)d_in[6];
    const float* w_o    = (const float*)d_in[7];
    const float* b_o    = (const float*)d_in[8];

    const int B = in_sizes[2];   // 32768 rows
    const int D = in_sizes[5];   // 1024 (kernel assumes 1024)

    float* out       = (float*)d_out;
    float* out_real  = out;
    float* out_imag  = out + (size_t)B * (size_t)D;
    float* out_alpha = out + 2ull * (size_t)B * (size_t)D;

    liquid_echo_kernel<<<B / 4, 256, 0, stream>>>(
        x_real, x_imag, t, mem_r, mem_i, w_q, b_q, w_o, b_o,
        out_real, out_imag, out_alpha);
}

// Round 4
// 140.510 us; speedup vs baseline: 1.0617x; 1.0436x over previous
//
#include <hip/hip_runtime.h>
#include <math.h>

typedef float f32x4 __attribute__((ext_vector_type(4)));

static constexpr float PHI_F = 1.61803398874989484820f;

// Forced-issue 16B load: asm volatile order is preserved by the compiler, so
// all bursts below are genuinely in flight together (cannot be sunk to uses).
// Consumption is guarded by explicit s_waitcnt + sched_barrier(0) (rule #18).
#define GLD(dst, p) asm volatile("global_load_dwordx4 %0, %1, off" : "=&v"(dst) : "v"(p))

__global__ __launch_bounds__(256) void liquid_echo_kernel(
    const float* __restrict__ x_real,
    const float* __restrict__ x_imag,
    const float* __restrict__ t,
    const float* __restrict__ mem_r,
    const float* __restrict__ mem_i,
    const float* __restrict__ w_query,
    const float* __restrict__ b_query,
    const float* __restrict__ w_osc,
    const float* __restrict__ b_osc,
    float* __restrict__ out_real,
    float* __restrict__ out_imag,
    float* __restrict__ out_alpha)
{
    const int tid  = threadIdx.x;
    const int lane = tid & 63;
    const int wave = tid >> 6;
    const int row  = (blockIdx.x << 2) + wave;      // one wave per row
    const size_t rbase = (size_t)row << 10;         // row * 1024

    const float trow = t[row];

    f32x4 xr[4], xi[4], mr[4], mi[4], wq[4], bq[4], wo[4], bo[4];

    // ---- burst, oldest-first by need ----
    // phase-1 streams (12 loads)
#pragma unroll
    for (int j = 0; j < 4; ++j) GLD(xr[j], x_real + rbase + (size_t)(((j << 6) + lane) << 2));
#pragma unroll
    for (int j = 0; j < 4; ++j) GLD(mr[j], mem_r + rbase + (size_t)(((j << 6) + lane) << 2));
#pragma unroll
    for (int j = 0; j < 4; ++j) GLD(mi[j], mem_i + rbase + (size_t)(((j << 6) + lane) << 2));
    // phase-1 weights (8 loads, L2-hot)
#pragma unroll
    for (int j = 0; j < 4; ++j) GLD(wq[j], w_query + (((j << 6) + lane) << 2));
#pragma unroll
    for (int j = 0; j < 4; ++j) GLD(bq[j], b_query + (((j << 6) + lane) << 2));
    // phase-2-only stream last (4 loads) — still in flight during phase 1
#pragma unroll
    for (int j = 0; j < 4; ++j) GLD(xi[j], x_imag + rbase + (size_t)(((j << 6) + lane) << 2));

    // wait for the oldest 20 (everything except the 4 x_imag loads)
    asm volatile("s_waitcnt vmcnt(4)" ::: "memory");
    __builtin_amdgcn_sched_barrier(0);

    // ---- phase 1: interference dot products (16 elems/lane) ----
    float accr = 0.f, acci = 0.f;
#pragma unroll
    for (int j = 0; j < 4; ++j) {
#pragma unroll
        for (int k = 0; k < 4; ++k) {
            float inv = __builtin_amdgcn_rcpf(1.0f + fabsf(wq[j][k]));
            float th  = fmaf(xr[j][k], inv, bq[j][k]);
            float s, c;
            __sincosf(th, &s, &c);
            accr = fmaf(c, mr[j][k], fmaf(s, mi[j][k], accr));
            acci = fmaf(c, mi[j][k], fmaf(-s, mr[j][k], acci));
        }
    }

    // phase-2 weights issued now: latency hides under the shfl chain
#pragma unroll
    for (int j = 0; j < 4; ++j) GLD(wo[j], w_osc + (((j << 6) + lane) << 2));
#pragma unroll
    for (int j = 0; j < 4; ++j) GLD(bo[j], b_osc + (((j << 6) + lane) << 2));

    // ---- in-wave butterfly reduce: every lane gets the row sum ----
#pragma unroll
    for (int off = 32; off > 0; off >>= 1) {
        accr += __shfl_xor(accr, off, 64);
        acci += __shfl_xor(acci, off, 64);
    }

    // ---- alpha (scale = sqrt(1024) = 32) ----
    const float mag   = sqrtf(fmaf(accr, accr, acci * acci));
    const float z     = fmaf(mag, 1.0f / 32.0f, -2.0f);
    const float norm  = __builtin_amdgcn_rcpf(1.0f + __expf(-z));   // sigmoid(z)
    const float alpha = __expf(norm - 1.0f);                        // exp(-(1-norm))
    const float beta  = 1.0f - alpha;
    const float tphi2 = 2.0f * PHI_F * trow;

    // drain x_imag + wo/bo
    asm volatile("s_waitcnt vmcnt(0)" ::: "memory");
    __builtin_amdgcn_sched_barrier(0);

    // ---- phase 2: blend + oscillate; evolved = (cos,sin)(th_r + th_i) ----
#pragma unroll
    for (int j = 0; j < 4; ++j) {
        f32x4 er, ei;
#pragma unroll
        for (int k = 0; k < 4; ++k) {
            float br  = fmaf(alpha, xr[j][k], beta * mr[j][k]);
            float bi  = fmaf(alpha, xi[j][k], beta * mi[j][k]);
            float inv = __builtin_amdgcn_rcpf(1.0f + fabsf(wo[j][k]));
            float ths = fmaf(br + bi, inv, fmaf(2.0f, bo[j][k], tphi2));
            float s, c;
            __sincosf(ths, &s, &c);
            er[k] = c;
            ei[k] = s;
        }
        const size_t off = rbase + (size_t)(((j << 6) + lane) << 2);
        // nontemporal: keep the LLC for the input streams
        __builtin_nontemporal_store(er, (f32x4*)(out_real + off));
        __builtin_nontemporal_store(ei, (f32x4*)(out_imag + off));
    }

    if (lane == 0) out_alpha[row] = alpha;
}

extern "C" void kernel_launch(void* const* d_in, const int* in_sizes, int n_in,
                              void* d_out, int out_size, void* d_ws, size_t ws_size,
                              hipStream_t stream) {
    const float* x_real = (const float*)d_in[0];
    const float* x_imag = (const float*)d_in[1];
    const float* t      = (const float*)d_in[2];
    const float* mem_r  = (const float*)d_in[3];
    const float* mem_i  = (const float*)d_in[4];
    const float* w_q    = (const float*)d_in[5];
    const float* b_q    = (const float*)d_in[6];
    const float* w_o    = (const float*)d_in[7];
    const float* b_o    = (const float*)d_in[8];

    const int B = in_sizes[2];   // 32768 rows
    const int D = in_sizes[5];   // 1024 (kernel assumes 1024)

    float* out       = (float*)d_out;
    float* out_real  = out;
    float* out_imag  = out + (size_t)B * (size_t)D;
    float* out_alpha = out + 2ull * (size_t)B * (size_t)D;

    liquid_echo_kernel<<<B / 4, 256, 0, stream>>>(
        x_real, x_imag, t, mem_r, mem_i, w_q, b_q, w_o, b_o,
        out_real, out_imag, out_alpha);
}